// Round 17
// baseline (134.115 us; speedup 1.0000x reference)
//
#include <hip/hip_runtime.h>
#include <cstdint>
#include <cmath>

#define B_ 2
#define N_ 4096
#define D_ 128
#define H_ 16
#define DQK_ 64
#define DV_ 256

typedef float    f4_t  __attribute__((ext_vector_type(4)));
typedef float    f16f  __attribute__((ext_vector_type(16)));
typedef _Float16 h4_t  __attribute__((ext_vector_type(4)));
typedef _Float16 h8_t  __attribute__((ext_vector_type(8)));

__device__ __forceinline__ float sigmoidf_(float z) { return 1.f/(1.f + expf(-z)); }
__device__ __forceinline__ float siluf_(float z)    { return z/(1.f + expf(-z)); }
__device__ __forceinline__ f16f zero16() {
  f16f z;
#pragma unroll
  for (int i = 0; i < 16; ++i) z[i] = 0.f;
  return z;
}
__device__ __forceinline__ h8_t cat8_(h4_t a, h4_t b) {
  return __builtin_shufflevector(a, b, 0, 1, 2, 3, 4, 5, 6, 7);
}

// ---------------- EMA: s[t] = q*s[t-1] + a*exp[h,d]*x[t], chunked scan ----------------
__global__ void ema_phase1(const float* __restrict__ x, const float* __restrict__ expansion,
                           const float* __restrict__ alphas, const float* __restrict__ dampen,
                           float* __restrict__ F, _Float16* __restrict__ xh) {
  int bid = blockIdx.x;
  int dg = bid & 7, c = (bid >> 3) & 63, b = bid >> 9;
  int h = threadIdx.x & 15, dl = threadIdx.x >> 4;
  int d = dg*16 + dl;
  float a  = sigmoidf_(alphas[h]);
  float dm = sigmoidf_(dampen[h]);
  float q  = (1.f - a)*dm;
  float coef = a * expansion[h*D_ + d];
  __shared__ float xs[64][16];
  {
    int e = threadIdx.x;
    int t = e >> 2, seg = e & 3;
    const float* xp = x + ((size_t)b*N_ + c*64 + t)*D_ + dg*16 + seg*4;
    f4_t v = *(const f4_t*)xp;
    *(f4_t*)&xs[t][seg*4] = v;
    h4_t hv;
#pragma unroll
    for (int j = 0; j < 4; ++j) hv[j] = (_Float16)v[j];
    *(h4_t*)(xh + ((size_t)b*N_ + c*64 + t)*D_ + dg*16 + seg*4) = hv;
  }
  __syncthreads();
  float s = 0.f;
#pragma unroll
  for (int t = 0; t < 64; ++t) s = fmaf(q, s, coef*xs[t][dl]);
  F[(((size_t)b*H_ + h)*D_ + d)*64 + c] = s;
}

// wave-parallel affine scan over 64 chunks: one wave per (b,h,d). grid 1024 x 256.
__global__ void ema_carry(const float* __restrict__ F, const float* __restrict__ alphas,
                          const float* __restrict__ dampen, float* __restrict__ carry) {
  int wid = blockIdx.x*4 + (threadIdx.x >> 6);  // 0..4095 = (b*16+h)*128 + d
  int lane = threadIdx.x & 63;
  int h = (wid >> 7) & 15;
  float a  = sigmoidf_(alphas[h]);
  float dm = sigmoidf_(dampen[h]);
  float q  = (1.f - a)*dm;
  float qL = q;
#pragma unroll
  for (int i = 0; i < 6; ++i) qL *= qL;        // q^64
  float A = qL;
  float Bv = F[(size_t)wid*64 + lane];
#pragma unroll
  for (int len = 1; len < 64; len <<= 1) {
    float Ap = __shfl_up(A, len);
    float Bp = __shfl_up(Bv, len);
    if (lane >= len) { Bv = fmaf(A, Bp, Bv); A = A*Ap; }
  }
  float Bprev = __shfl_up(Bv, 1);
  carry[(size_t)wid*64 + lane] = (lane == 0) ? 0.f : Bprev;
}

__global__ void ema_phase2(const float* __restrict__ x, const float* __restrict__ expansion,
                           const float* __restrict__ reduction,
                           const float* __restrict__ alphas, const float* __restrict__ dampen,
                           const float* __restrict__ carry, _Float16* __restrict__ emah) {
  int bid = blockIdx.x;
  int dg = bid & 7, c = (bid >> 3) & 63, b = bid >> 9;
  int h = threadIdx.x & 15, dl = threadIdx.x >> 4;
  int d = dg*16 + dl;
  float a  = sigmoidf_(alphas[h]);
  float dm = sigmoidf_(dampen[h]);
  float q  = (1.f - a)*dm;
  float coef = a * expansion[h*D_ + d];
  float red  = reduction[h*D_ + d];
  __shared__ float xs[64][16];
  {
    int e = threadIdx.x;
    int t = e >> 2, seg = e & 3;
    const float* xp = x + ((size_t)b*N_ + c*64 + t)*D_ + dg*16 + seg*4;
    *(f4_t*)&xs[t][seg*4] = *(const f4_t*)xp;
  }
  __syncthreads();
  float s = carry[(((size_t)b*H_ + h)*D_ + d)*64 + c];
  for (int t = 0; t < 64; ++t) {
    s = fmaf(q, s, coef*xs[t][dl]);
    float v = red * s;
    v += __shfl_xor(v, 1); v += __shfl_xor(v, 2);
    v += __shfl_xor(v, 4); v += __shfl_xor(v, 8);
    if (h == 0) emah[((size_t)b*N_ + c*64 + t)*D_ + d] = (_Float16)v;
  }
}

// ------- merged prep: Wt[832][128] f16 + bcat, Uht[128][256] f16, bias2T[4096] -------
__global__ void prep_all(const float* __restrict__ Wqk, const float* __restrict__ Wv,
                         const float* __restrict__ Wr, const float* __restrict__ Wu,
                         const float* __restrict__ Wh,
                         const float* __restrict__ bqk, const float* __restrict__ bv,
                         const float* __restrict__ br, const float* __restrict__ bu,
                         const float* __restrict__ bh,
                         const float* __restrict__ Uh, const float* __restrict__ rel_table,
                         _Float16* __restrict__ Wt, float* __restrict__ bcat,
                         _Float16* __restrict__ Uht, float* __restrict__ bias2T) {
  int idx = blockIdx.x*256 + threadIdx.x;
  if (idx < 832*128) {
    int c = idx >> 7, d = idx & 127;
    const float* W; const float* bias; int ncol, cl;
    if (c < 64)       { W=Wqk; bias=bqk; ncol=64;  cl=c; }
    else if (c < 320) { W=Wv;  bias=bv;  ncol=256; cl=c-64; }
    else if (c < 576) { W=Wr;  bias=br;  ncol=256; cl=c-320; }
    else if (c < 704) { W=Wu;  bias=bu;  ncol=128; cl=c-576; }
    else              { W=Wh;  bias=bh;  ncol=128; cl=c-704; }
    Wt[idx] = (_Float16)W[d*ncol + cl];
    if (d == 0) bcat[c] = bias[cl];
  } else if (idx < 832*128 + 32768) {
    int i2 = idx - 832*128;
    int k = i2 >> 7, c = i2 & 127;
    Uht[(size_t)c*256 + k] = (_Float16)Uh[i2];
  } else if (idx < 832*128 + 32768 + 4096) {
    int r = idx - (832*128 + 32768);
    int bucket;
    if (r < 16) bucket = r;
    else {
      double v = log((double)r / 16.0) / log(8.0) * 16.0;
      bucket = 16 + (int)v;
      if (bucket > 31) bucket = 31;
    }
    bias2T[r] = (rel_table[bucket]*8.0f - 0.70710678f) * 1.1283792f;
  }
}

// ---------------- fused linears as MFMA GEMM: [8192 x 128] @ [128 x 832] ----------------
// V output goes to j-tiled layout vTt[b][jt 128][dv 256][j 32] f16 (contiguous 16KB tiles).
// Uses gfx950-native 16x16x32 MFMA.
__global__ __launch_bounds__(256) void linear_mfma(
    const _Float16* __restrict__ emah, const _Float16* __restrict__ xh,
    const _Float16* __restrict__ Wt, const float* __restrict__ bcat,
    const float* __restrict__ gamma, const float* __restrict__ beta,
    _Float16* __restrict__ qh, _Float16* __restrict__ kh, _Float16* __restrict__ vTt,
    _Float16* __restrict__ resetbh, _Float16* __restrict__ updatebh,
    float* __restrict__ hemab) {
  int slab = blockIdx.x % 13, rt = blockIdx.x / 13;
  int tid = threadIdx.x;
  int lane = tid & 63, w = tid >> 6;
  int lr = lane & 15, lg = lane >> 4;
  int mode = (slab==0)?0:(slab<5)?1:(slab<9)?2:(slab<11)?3:4;
  const _Float16* src = (mode==1) ? xh : emah;
  __shared__ _Float16 As[64][136];
  __shared__ _Float16 Ws[64][136];
  {
    const h8_t* s8 = (const h8_t*)(src + (size_t)rt*64*D_);
#pragma unroll
    for (int i = 0; i < 4; ++i) {
      int idx = tid + i*256;
      int row = idx >> 4, seg = idx & 15;
      *(h8_t*)&As[row][seg*8] = s8[idx];
    }
    const h8_t* w8 = (const h8_t*)(Wt + (size_t)slab*64*D_);
#pragma unroll
    for (int i = 0; i < 4; ++i) {
      int idx = tid + i*256;
      int row = idx >> 4, seg = idx & 15;
      *(h8_t*)&Ws[row][seg*8] = w8[idx];
    }
  }
  __syncthreads();
  h8_t af8[4];
#pragma unroll
  for (int kk = 0; kk < 4; ++kk) af8[kk] = *(const h8_t*)&As[w*16 + lr][32*kk + 8*lg];
  int row0 = rt*64 + w*16 + lg*4;
#pragma unroll
  for (int ns = 0; ns < 4; ++ns) {
    f4_t acc = (f4_t){0.f,0.f,0.f,0.f};
#pragma unroll
    for (int kk = 0; kk < 4; ++kk) {
      h8_t bf8 = *(const h8_t*)&Ws[ns*16 + lr][32*kk + 8*lg];
      acc = __builtin_amdgcn_mfma_f32_16x16x32_f16(af8[kk], bf8, acc, 0, 0, 0);
    }
    int c = slab*64 + ns*16 + lr;
    float bias = bcat[c];
    if (mode == 0) {
      float g0 = gamma[c], g1 = gamma[64+c], be0 = beta[c], be1 = beta[64+c];
#pragma unroll
      for (int r = 0; r < 4; ++r) {
        float qk = siluf_(acc[r] + bias);
        size_t row = row0 + r;
        qh[row*DQK_ + c] = (_Float16)(qk*g0 + be0);
        kh[row*DQK_ + c] = (_Float16)(qk*g1 + be1);
      }
    } else if (mode == 1) {
      int cl = c - 64;
      int bb = row0 >> 12, rl = row0 & 4095;
      h4_t vv;
#pragma unroll
      for (int r = 0; r < 4; ++r) vv[r] = (_Float16)siluf_(acc[r] + bias);
      *(h4_t*)&vTt[(((size_t)bb*128 + (rl>>5))*256 + cl)*32 + (rl&31)] = vv;
    } else if (mode == 2) {
      int cl = c - 320;
#pragma unroll
      for (int r = 0; r < 4; ++r)
        resetbh[(size_t)(row0 + r)*DV_ + cl] = (_Float16)siluf_(acc[r] + bias);
    } else if (mode == 3) {
      int cl = c - 576;
#pragma unroll
      for (int r = 0; r < 4; ++r)
        updatebh[(size_t)(row0 + r)*D_ + cl] = (_Float16)sigmoidf_(acc[r] + bias);
    } else {
      int cl = c - 704;
#pragma unroll
      for (int r = 0; r < 4; ++r) hemab[(size_t)(row0 + r)*D_ + cl] = acc[r] + bias;
    }
  }
}

// ---------------- attention: laplacianCDF(QK^T/n + bias) @ V, causal, 32x32x16 MFMA ------
// grid 2048 = 64(it) x 16(s) x 2(b). block 256 = 4 waves = (ih, dvh).
// Producer/consumer split; P relay as [32 i][36 j] tile; packed b64 P-stores.
__global__ __launch_bounds__(256, 3) void attn_kernel(
    const _Float16* __restrict__ qh, const _Float16* __restrict__ kh,
    const _Float16* __restrict__ vTt, const float* __restrict__ bias2T,
    _Float16* __restrict__ attnp) {
  int bid = blockIdx.x;
  int it = 63 - (bid >> 5);
  int rem = bid & 31;
  int s = rem >> 1, b = rem & 1;
  int a = it >> 2, r = it & 3;
  int nblk = a + 1;
  if (s >= nblk) return;
  int T = 2*it + 2;
  int tlo = (s*T)/nblk, thi = ((s+1)*T)/nblk;
  int nt = thi - tlo;
  int base = it + 2*a*(a-1) + r*a;
  int slot = base + s;
  int i0 = it * 64;
  int tid = threadIdx.x;
  int lane = tid & 63, w = tid >> 6;
  int ih = w & 1;
  int dvh = w >> 1;
  bool prod = (dvh == 0);
  int lm = lane & 31, lg = lane >> 5;

  __shared__ __align__(16) char Vb[2][18432];   // V [256 dv][36 f16] stride 72B (2-way free)
  __shared__ __align__(16) char Kb[2][4352];    // K [32 j][68 f16] stride 136B
  __shared__ __align__(16) char Pbuf[2][2304];  // P per ih: [32 i][36 f16] stride 72B
  __shared__ float biasW[320];

  int jmaxv = thi*32 - 1;
  int dlo = i0 - jmaxv;
  int cnt = 64 + jmaxv - tlo*32;                // <= 320
  for (int k = tid; k < cnt; k += 256) {
    int d = dlo + k;
    biasW[k] = d < 0 ? -1e38f : bias2T[d];      // causal fold: -1e38 -> pv = 0
  }

  h8_t qf8[4];
  if (prod) {
    const _Float16* qp = qh + ((size_t)b*N_ + i0 + ih*32 + lm)*DQK_ + 8*lg;
#pragma unroll
    for (int kk = 0; kk < 4; ++kk) qf8[kk] = *(const h8_t*)(qp + 16*kk);
  }

  f16f accO[4];
#pragma unroll
  for (int i = 0; i < 4; ++i) accO[i] = zero16();

  const _Float16* kbase = kh + (size_t)b*N_*DQK_;
  const _Float16* vbase = vTt + (size_t)b*128*8192;   // 8192 f16 per 32-j tile
  int st = tid & 127;                           // stager index (threads 128..255)
  int kr = st >> 2, ks16 = st & 3;

  h8_t k8a, k8b, vr[8];
#define ISSUE_(JT) { \
  const _Float16* kp_ = kbase + (size_t)((JT)*32 + kr)*DQK_ + ks16*16; \
  k8a = *(const h8_t*)kp_; k8b = *(const h8_t*)(kp_ + 8); \
  const _Float16* vp_ = vbase + (size_t)(JT)*8192 + st*32; \
  _Pragma("unroll") for (int i = 0; i < 4; ++i) vr[i] = *(const h8_t*)(vp_ + i*8); \
  _Pragma("unroll") for (int i = 0; i < 4; ++i) vr[4+i] = *(const h8_t*)(vp_ + 4096 + i*8); }

#define COMMIT_(BI) { \
  char* kb_ = Kb[BI] + kr*136 + ks16*32; \
  *(h4_t*)kb_        = __builtin_shufflevector(k8a, k8a, 0,1,2,3); \
  *(h4_t*)(kb_ + 8)  = __builtin_shufflevector(k8a, k8a, 4,5,6,7); \
  *(h4_t*)(kb_ + 16) = __builtin_shufflevector(k8b, k8b, 0,1,2,3); \
  *(h4_t*)(kb_ + 24) = __builtin_shufflevector(k8b, k8b, 4,5,6,7); \
  char* va_ = Vb[BI] + st*72; \
  _Pragma("unroll") for (int i = 0; i < 4; ++i) { \
    *(h4_t*)(va_ + i*16)     = __builtin_shufflevector(vr[i], vr[i], 0,1,2,3); \
    *(h4_t*)(va_ + i*16 + 8) = __builtin_shufflevector(vr[i], vr[i], 4,5,6,7); } \
  char* vb2_ = Vb[BI] + (st + 128)*72; \
  _Pragma("unroll") for (int i = 0; i < 4; ++i) { \
    *(h4_t*)(vb2_ + i*16)     = __builtin_shufflevector(vr[4+i], vr[4+i], 0,1,2,3); \
    *(h4_t*)(vb2_ + i*16 + 8) = __builtin_shufflevector(vr[4+i], vr[4+i], 4,5,6,7); } }

  // prologue (stagers only): tile 0 committed; tile 1 in flight
  if (!prod) {
    ISSUE_(tlo);
    COMMIT_(0);
    if (nt > 1) ISSUE_(tlo + 1);
  }
  __syncthreads();

  const float C1 = 1.1283792f / 4096.f;
  int ibase = i0 + ih*32 + lm;
#pragma unroll 1
  for (int t = 0; t < nt; ++t) {
    if (prod) {
      // QK: S^T = sum_k mfma(K_frag, Q_frag), rows j cols i  (32x32x16, 4 MFMAs)
      const char* kb = Kb[t & 1];
      __builtin_amdgcn_s_setprio(1);
      f16f accS = zero16();
#pragma unroll
      for (int kk = 0; kk < 4; ++kk) {
        const char* ka = kb + lm*136 + 32*kk + 16*lg;
        h8_t kf8 = cat8_(*(const h4_t*)ka, *(const h4_t*)(ka + 8));
        accS = __builtin_amdgcn_mfma_f32_32x32x16_f16(kf8, qf8[kk], accS, 0, 0, 0);
      }
      __builtin_amdgcn_s_setprio(0);
      // softmax (once); pack per-k2 h4 groups (jl = 8*k2 + 4*lg + e) -> 4 b64 stores
      int idx0 = ibase - dlo - (tlo + t)*32 - 4*lg;
      h4_t pa[4];
#pragma unroll
      for (int rr = 0; rr < 16; ++rr) {
        float tt = fmaf(accS[rr], C1, biasW[idx0 - 8*(rr>>2) - (rr&3)]);
        float e = tt*fmaf(tt*tt, -0.101797f, -2.304877f);
        float u = exp2f(e);
        float pv = __builtin_amdgcn_rcpf(1.f + u);
        pa[rr>>2][rr&3] = (_Float16)pv;
      }
      char* pp = Pbuf[ih] + lm*72 + 8*lg;
#pragma unroll
      for (int k2 = 0; k2 < 4; ++k2) *(h4_t*)(pp + 16*k2) = pa[k2];
    } else {
      // stagers: distance-2 pipeline (commit tile t+1 issued one tile ago; issue t+2)
      if (t+1 < nt) COMMIT_((t+1) & 1);
      if (t+2 < nt) ISSUE_(tlo + t + 2);
    }
    __syncthreads();                            // B1: P + V/K(t+1) published
    // all waves: read P as PV A-fragments (row i=lm, k j = 16*ks2 + 8*lg + e)
    h8_t pa8[2];
    {
      const char* pp = Pbuf[ih] + lm*72;
#pragma unroll
      for (int ks2 = 0; ks2 < 2; ++ks2) {
        const char* pa_ = pp + 32*ks2 + 16*lg;
        pa8[ks2] = cat8_(*(const h4_t*)pa_, *(const h4_t*)(pa_ + 8));
      }
    }
    // PV: O += P @ V (this wave's dv half), 32x32x16, 8 MFMAs
    const char* vb = Vb[t & 1];
    __builtin_amdgcn_s_setprio(1);
#pragma unroll
    for (int ks2 = 0; ks2 < 2; ++ks2) {
#pragma unroll
      for (int dvb = 0; dvb < 4; ++dvb) {
        const char* va = vb + (dvh*128 + dvb*32 + lm)*72 + 32*ks2 + 16*lg;
        h8_t vf8 = cat8_(*(const h4_t*)va, *(const h4_t*)(va + 8));
        accO[dvb] = __builtin_amdgcn_mfma_f32_32x32x16_f16(pa8[ks2], vf8, accO[dvb], 0, 0, 0);
      }
    }
    __builtin_amdgcn_s_setprio(0);
    __syncthreads();                            // B2: reads of Vb[t&1]/Pbuf done
  }
#undef ISSUE_
#undef COMMIT_

  _Float16* op = attnp + ((size_t)b*544 + slot)*(64*256);
#pragma unroll
  for (int dvb = 0; dvb < 4; ++dvb) {
    int col = dvh*128 + dvb*32 + lm;
#pragma unroll
    for (int rr = 0; rr < 16; ++rr) {
      int row = ih*32 + 8*(rr>>2) + 4*lg + (rr&3);
      op[(size_t)row*256 + col] = (_Float16)accO[dvb][rr];
    }
  }
}

// ---------------- final (fused combine): A = (sum attn partials) * reset; ----------------
// H = silu(hemab + A@Uh); out = u*H + (1-u)*x. Each 64-row tile maps to ONE (b,it) group.
// grid 256 = 128 rowtiles (largest-nblk first) x 2 colslabs.
__global__ __launch_bounds__(256) void final_mfma(
    const _Float16* __restrict__ attnp, const _Float16* __restrict__ resetbh,
    const _Float16* __restrict__ Uht, const float* __restrict__ hemab,
    const _Float16* __restrict__ updatebh, const float* __restrict__ x,
    float* __restrict__ out) {
  int rt = 127 - (blockIdx.x >> 1);             // largest it first
  int cs = blockIdx.x & 1;
  int tid = threadIdx.x;
  int lane = tid & 63, w = tid >> 6;
  int lr = lane & 15, lg = lane >> 4;
  int row0 = rt*64, c0 = cs*64;
  int b = rt >> 6, it = rt & 63;
  int a = it >> 2, r = it & 3;
  int nblk = a + 1;
  int base = it + 2*a*(a-1) + r*a;
  const _Float16* ap0 = attnp + ((size_t)b*544 + base)*16384;
  __shared__ _Float16 As[64][136];
  __shared__ _Float16 Ws[64][136];
  f4_t acc[4];
#pragma unroll
  for (int ns = 0; ns < 4; ++ns) acc[ns] = (f4_t){0.f,0.f,0.f,0.f};
#pragma unroll
  for (int kc = 0; kc < 2; ++kc) {
    __syncthreads();
#pragma unroll
    for (int i = 0; i < 4; ++i) {
      int idx = tid + i*256;
      int row = idx >> 4, seg = idx & 15;
      int col = kc*128 + seg*8;
      // A = (sum of f16 partial slots, f32 accum) * reset
      const _Float16* ap = ap0 + row*256 + col;
      float s8[8];
#pragma unroll
      for (int j = 0; j < 8; ++j) s8[j] = 0.f;
      for (int s2 = 0; s2 < nblk; ++s2) {
        h8_t pv = *(const h8_t*)(ap + (size_t)s2*16384);
#pragma unroll
        for (int j = 0; j < 8; ++j) s8[j] += (float)pv[j];
      }
      h8_t rg = *(const h8_t*)(resetbh + (size_t)(row0 + row)*DV_ + col);
      h8_t ga;
#pragma unroll
      for (int j = 0; j < 8; ++j) ga[j] = (_Float16)(s8[j] * (float)rg[j]);
      *(h8_t*)&As[row][seg*8] = ga;
      *(h8_t*)&Ws[row][seg*8] =
          *(const h8_t*)(Uht + (size_t)(c0 + row)*DV_ + kc*128 + seg*8);
    }
    __syncthreads();
    h8_t af8[4];
#pragma unroll
    for (int kk = 0; kk < 4; ++kk) af8[kk] = *(const h8_t*)&As[w*16 + lr][32*kk + 8*lg];
#pragma unroll
    for (int ns = 0; ns < 4; ++ns) {
#pragma unroll
      for (int kk = 0; kk < 4; ++kk) {
        h8_t bf8 = *(const h8_t*)&Ws[ns*16 + lr][32*kk + 8*lg];
        acc[ns] = __builtin_amdgcn_mfma_f32_16x16x32_f16(af8[kk], bf8, acc[ns], 0, 0, 0);
      }
    }
  }
  int orow = row0 + w*16 + lg*4;
#pragma unroll
  for (int ns = 0; ns < 4; ++ns) {
    int col = c0 + ns*16 + lr;
#pragma unroll
    for (int r2 = 0; r2 < 4; ++r2) {
      size_t o = (size_t)(orow + r2)*D_ + col;
      float z = acc[ns][r2] + hemab[o];
      float Hv = siluf_(z);
      float u  = (float)updatebh[o];
      out[o] = u*Hv + (1.f - u)*x[o];
    }
  }
}

extern "C" void kernel_launch(void* const* d_in, const int* in_sizes, int n_in,
                              void* d_out, int out_size, void* d_ws, size_t ws_size,
                              hipStream_t stream) {
  (void)in_sizes; (void)n_in; (void)out_size; (void)ws_size;
  const float* x         = (const float*)d_in[0];
  const float* expansion = (const float*)d_in[1];
  const float* reduction = (const float*)d_in[2];
  const float* alphas    = (const float*)d_in[3];
  const float* dampen    = (const float*)d_in[4];
  const float* Wqk       = (const float*)d_in[5];
  const float* bqk       = (const float*)d_in[6];
  const float* gamma     = (const float*)d_in[7];
  const float* beta      = (const float*)d_in[8];
  const float* Wv        = (const float*)d_in[9];
  const float* bv        = (const float*)d_in[10];
  const float* rel_table = (const float*)d_in[11];
  const float* Wr        = (const float*)d_in[12];
  const float* br        = (const float*)d_in[13];
  const float* Wu        = (const float*)d_in[14];
  const float* bu        = (const float*)d_in[15];
  const float* Wh        = (const float*)d_in[16];
  const float* Uh        = (const float*)d_in[17];
  const float* bh        = (const float*)d_in[18];
  float* out = (float*)d_out;

  char* p = (char*)d_ws;
  size_t off = 0;
  auto alloc = [&](size_t bytes) -> char* {
    char* r = p + off;
    off += (bytes + 255) & ~(size_t)255;
    return r;
  };
  float*    F       = (float*)alloc((size_t)B_*H_*D_*64*4);
  float*    carry   = (float*)alloc((size_t)B_*H_*D_*64*4);
  _Float16* emah    = (_Float16*)alloc((size_t)B_*N_*D_*2);
  _Float16* xh      = (_Float16*)alloc((size_t)B_*N_*D_*2);
  float*    bias2T  = (float*)alloc((size_t)N_*4);
  _Float16* Wt      = (_Float16*)alloc((size_t)832*128*2);
  float*    bcat    = (float*)alloc((size_t)832*4);
  _Float16* Uht     = (_Float16*)alloc((size_t)D_*DV_*2);
  _Float16* qh      = (_Float16*)alloc((size_t)B_*N_*DQK_*2);
  _Float16* kh      = (_Float16*)alloc((size_t)B_*N_*DQK_*2);
  _Float16* vTt     = (_Float16*)alloc((size_t)B_*DV_*N_*2);
  _Float16* resetbh = (_Float16*)alloc((size_t)B_*N_*DV_*2);
  _Float16* updatebh= (_Float16*)alloc((size_t)B_*N_*D_*2);
  float*    hemab   = (float*)alloc((size_t)B_*N_*D_*4);
  _Float16* attnp   = (_Float16*)alloc((size_t)B_*544*64*256*2);

  prep_all<<<560, 256, 0, stream>>>(Wqk, Wv, Wr, Wu, Wh, bqk, bv, br, bu, bh,
                                    Uh, rel_table, Wt, bcat, Uht, bias2T);
  ema_phase1<<<1024, 256, 0, stream>>>(x, expansion, alphas, dampen, F, xh);
  ema_carry<<<1024, 256, 0, stream>>>(F, alphas, dampen, carry);
  ema_phase2<<<1024, 256, 0, stream>>>(x, expansion, reduction, alphas, dampen, carry, emah);
  linear_mfma<<<128*13, 256, 0, stream>>>(emah, xh, Wt, bcat, gamma, beta,
                                          qh, kh, vTt, resetbh, updatebh, hemab);
  attn_kernel<<<2048, 256, 0, stream>>>(qh, kh, vTt, bias2T, attnp);
  final_mfma<<<256, 256, 0, stream>>>(attnp, resetbh, Uht, hemab, updatebh, x, out);
}

// Round 18
// 100.665 us; speedup vs baseline: 1.3323x; 1.3323x over previous
//
#include <hip/hip_runtime.h>
#include <cstdint>
#include <cmath>

#define B_ 2
#define N_ 4096
#define D_ 128
#define H_ 16
#define DQK_ 64
#define DV_ 256

typedef float    f4_t  __attribute__((ext_vector_type(4)));
typedef float    f16f  __attribute__((ext_vector_type(16)));
typedef _Float16 h4_t  __attribute__((ext_vector_type(4)));
typedef _Float16 h8_t  __attribute__((ext_vector_type(8)));

__device__ __forceinline__ float sigmoidf_(float z) { return 1.f/(1.f + expf(-z)); }
__device__ __forceinline__ float siluf_(float z)    { return z/(1.f + expf(-z)); }
__device__ __forceinline__ f16f zero16() {
  f16f z;
#pragma unroll
  for (int i = 0; i < 16; ++i) z[i] = 0.f;
  return z;
}
__device__ __forceinline__ h8_t cat8_(h4_t a, h4_t b) {
  return __builtin_shufflevector(a, b, 0, 1, 2, 3, 4, 5, 6, 7);
}

// ---------------- EMA: s[t] = q*s[t-1] + a*exp[h,d]*x[t], chunked scan ----------------
__global__ void ema_phase1(const float* __restrict__ x, const float* __restrict__ expansion,
                           const float* __restrict__ alphas, const float* __restrict__ dampen,
                           float* __restrict__ F, _Float16* __restrict__ xh) {
  int bid = blockIdx.x;
  int dg = bid & 7, c = (bid >> 3) & 63, b = bid >> 9;
  int h = threadIdx.x & 15, dl = threadIdx.x >> 4;
  int d = dg*16 + dl;
  float a  = sigmoidf_(alphas[h]);
  float dm = sigmoidf_(dampen[h]);
  float q  = (1.f - a)*dm;
  float coef = a * expansion[h*D_ + d];
  __shared__ float xs[64][16];
  {
    int e = threadIdx.x;
    int t = e >> 2, seg = e & 3;
    const float* xp = x + ((size_t)b*N_ + c*64 + t)*D_ + dg*16 + seg*4;
    f4_t v = *(const f4_t*)xp;
    *(f4_t*)&xs[t][seg*4] = v;
    h4_t hv;
#pragma unroll
    for (int j = 0; j < 4; ++j) hv[j] = (_Float16)v[j];
    *(h4_t*)(xh + ((size_t)b*N_ + c*64 + t)*D_ + dg*16 + seg*4) = hv;
  }
  __syncthreads();
  float s = 0.f;
#pragma unroll
  for (int t = 0; t < 64; ++t) s = fmaf(q, s, coef*xs[t][dl]);
  F[(((size_t)b*H_ + h)*D_ + d)*64 + c] = s;
}

// wave-parallel affine scan over 64 chunks: one wave per (b,h,d). grid 1024 x 256.
__global__ void ema_carry(const float* __restrict__ F, const float* __restrict__ alphas,
                          const float* __restrict__ dampen, float* __restrict__ carry) {
  int wid = blockIdx.x*4 + (threadIdx.x >> 6);  // 0..4095 = (b*16+h)*128 + d
  int lane = threadIdx.x & 63;
  int h = (wid >> 7) & 15;
  float a  = sigmoidf_(alphas[h]);
  float dm = sigmoidf_(dampen[h]);
  float q  = (1.f - a)*dm;
  float qL = q;
#pragma unroll
  for (int i = 0; i < 6; ++i) qL *= qL;        // q^64
  float A = qL;
  float Bv = F[(size_t)wid*64 + lane];
#pragma unroll
  for (int len = 1; len < 64; len <<= 1) {
    float Ap = __shfl_up(A, len);
    float Bp = __shfl_up(Bv, len);
    if (lane >= len) { Bv = fmaf(A, Bp, Bv); A = A*Ap; }
  }
  float Bprev = __shfl_up(Bv, 1);
  carry[(size_t)wid*64 + lane] = (lane == 0) ? 0.f : Bprev;
}

__global__ void ema_phase2(const float* __restrict__ x, const float* __restrict__ expansion,
                           const float* __restrict__ reduction,
                           const float* __restrict__ alphas, const float* __restrict__ dampen,
                           const float* __restrict__ carry, _Float16* __restrict__ emah) {
  int bid = blockIdx.x;
  int dg = bid & 7, c = (bid >> 3) & 63, b = bid >> 9;
  int h = threadIdx.x & 15, dl = threadIdx.x >> 4;
  int d = dg*16 + dl;
  float a  = sigmoidf_(alphas[h]);
  float dm = sigmoidf_(dampen[h]);
  float q  = (1.f - a)*dm;
  float coef = a * expansion[h*D_ + d];
  float red  = reduction[h*D_ + d];
  __shared__ float xs[64][16];
  {
    int e = threadIdx.x;
    int t = e >> 2, seg = e & 3;
    const float* xp = x + ((size_t)b*N_ + c*64 + t)*D_ + dg*16 + seg*4;
    *(f4_t*)&xs[t][seg*4] = *(const f4_t*)xp;
  }
  __syncthreads();
  float s = carry[(((size_t)b*H_ + h)*D_ + d)*64 + c];
  for (int t = 0; t < 64; ++t) {
    s = fmaf(q, s, coef*xs[t][dl]);
    float v = red * s;
    v += __shfl_xor(v, 1); v += __shfl_xor(v, 2);
    v += __shfl_xor(v, 4); v += __shfl_xor(v, 8);
    if (h == 0) emah[((size_t)b*N_ + c*64 + t)*D_ + d] = (_Float16)v;
  }
}

// ------- merged prep: Wt[832][128] f16 + bcat, Uht[128][256] f16, bias2T[4096] -------
__global__ void prep_all(const float* __restrict__ Wqk, const float* __restrict__ Wv,
                         const float* __restrict__ Wr, const float* __restrict__ Wu,
                         const float* __restrict__ Wh,
                         const float* __restrict__ bqk, const float* __restrict__ bv,
                         const float* __restrict__ br, const float* __restrict__ bu,
                         const float* __restrict__ bh,
                         const float* __restrict__ Uh, const float* __restrict__ rel_table,
                         _Float16* __restrict__ Wt, float* __restrict__ bcat,
                         _Float16* __restrict__ Uht, float* __restrict__ bias2T) {
  int idx = blockIdx.x*256 + threadIdx.x;
  if (idx < 832*128) {
    int c = idx >> 7, d = idx & 127;
    const float* W; const float* bias; int ncol, cl;
    if (c < 64)       { W=Wqk; bias=bqk; ncol=64;  cl=c; }
    else if (c < 320) { W=Wv;  bias=bv;  ncol=256; cl=c-64; }
    else if (c < 576) { W=Wr;  bias=br;  ncol=256; cl=c-320; }
    else if (c < 704) { W=Wu;  bias=bu;  ncol=128; cl=c-576; }
    else              { W=Wh;  bias=bh;  ncol=128; cl=c-704; }
    Wt[idx] = (_Float16)W[d*ncol + cl];
    if (d == 0) bcat[c] = bias[cl];
  } else if (idx < 832*128 + 32768) {
    int i2 = idx - 832*128;
    int k = i2 >> 7, c = i2 & 127;
    Uht[(size_t)c*256 + k] = (_Float16)Uh[i2];
  } else if (idx < 832*128 + 32768 + 4096) {
    int r = idx - (832*128 + 32768);
    int bucket;
    if (r < 16) bucket = r;
    else {
      double v = log((double)r / 16.0) / log(8.0) * 16.0;
      bucket = 16 + (int)v;
      if (bucket > 31) bucket = 31;
    }
    bias2T[r] = (rel_table[bucket]*8.0f - 0.70710678f) * 1.1283792f;
  }
}

// ---------------- fused linears as MFMA GEMM: [8192 x 128] @ [128 x 832] ----------------
// V output goes to j-tiled layout vTt[b][jt 128][dv 256][j 32] f16 (contiguous 16KB tiles).
// Uses gfx950-native 16x16x32 MFMA.
__global__ __launch_bounds__(256) void linear_mfma(
    const _Float16* __restrict__ emah, const _Float16* __restrict__ xh,
    const _Float16* __restrict__ Wt, const float* __restrict__ bcat,
    const float* __restrict__ gamma, const float* __restrict__ beta,
    _Float16* __restrict__ qh, _Float16* __restrict__ kh, _Float16* __restrict__ vTt,
    _Float16* __restrict__ resetbh, _Float16* __restrict__ updatebh,
    _Float16* __restrict__ hemabh) {
  int slab = blockIdx.x % 13, rt = blockIdx.x / 13;
  int tid = threadIdx.x;
  int lane = tid & 63, w = tid >> 6;
  int lr = lane & 15, lg = lane >> 4;
  int mode = (slab==0)?0:(slab<5)?1:(slab<9)?2:(slab<11)?3:4;
  const _Float16* src = (mode==1) ? xh : emah;
  __shared__ _Float16 As[64][136];
  __shared__ _Float16 Ws[64][136];
  {
    const h8_t* s8 = (const h8_t*)(src + (size_t)rt*64*D_);
#pragma unroll
    for (int i = 0; i < 4; ++i) {
      int idx = tid + i*256;
      int row = idx >> 4, seg = idx & 15;
      *(h8_t*)&As[row][seg*8] = s8[idx];
    }
    const h8_t* w8 = (const h8_t*)(Wt + (size_t)slab*64*D_);
#pragma unroll
    for (int i = 0; i < 4; ++i) {
      int idx = tid + i*256;
      int row = idx >> 4, seg = idx & 15;
      *(h8_t*)&Ws[row][seg*8] = w8[idx];
    }
  }
  __syncthreads();
  h8_t af8[4];
#pragma unroll
  for (int kk = 0; kk < 4; ++kk) af8[kk] = *(const h8_t*)&As[w*16 + lr][32*kk + 8*lg];
  int row0 = rt*64 + w*16 + lg*4;
#pragma unroll
  for (int ns = 0; ns < 4; ++ns) {
    f4_t acc = (f4_t){0.f,0.f,0.f,0.f};
#pragma unroll
    for (int kk = 0; kk < 4; ++kk) {
      h8_t bf8 = *(const h8_t*)&Ws[ns*16 + lr][32*kk + 8*lg];
      acc = __builtin_amdgcn_mfma_f32_16x16x32_f16(af8[kk], bf8, acc, 0, 0, 0);
    }
    int c = slab*64 + ns*16 + lr;
    float bias = bcat[c];
    if (mode == 0) {
      float g0 = gamma[c], g1 = gamma[64+c], be0 = beta[c], be1 = beta[64+c];
#pragma unroll
      for (int r = 0; r < 4; ++r) {
        float qk = siluf_(acc[r] + bias);
        size_t row = row0 + r;
        qh[row*DQK_ + c] = (_Float16)(qk*g0 + be0);
        kh[row*DQK_ + c] = (_Float16)(qk*g1 + be1);
      }
    } else if (mode == 1) {
      int cl = c - 64;
      int bb = row0 >> 12, rl = row0 & 4095;
      h4_t vv;
#pragma unroll
      for (int r = 0; r < 4; ++r) vv[r] = (_Float16)siluf_(acc[r] + bias);
      *(h4_t*)&vTt[(((size_t)bb*128 + (rl>>5))*256 + cl)*32 + (rl&31)] = vv;
    } else if (mode == 2) {
      int cl = c - 320;
#pragma unroll
      for (int r = 0; r < 4; ++r)
        resetbh[(size_t)(row0 + r)*DV_ + cl] = (_Float16)siluf_(acc[r] + bias);
    } else if (mode == 3) {
      int cl = c - 576;
#pragma unroll
      for (int r = 0; r < 4; ++r)
        updatebh[(size_t)(row0 + r)*D_ + cl] = (_Float16)sigmoidf_(acc[r] + bias);
    } else {
      int cl = c - 704;
#pragma unroll
      for (int r = 0; r < 4; ++r)
        hemabh[(size_t)(row0 + r)*D_ + cl] = (_Float16)(acc[r] + bias);
    }
  }
}

// ---------------- attention: laplacianCDF(QK^T/n + bias) @ V, causal, 32x32x16 MFMA ------
// grid 2048 = 64(it) x 16(s) x 2(b). block 256 = 4 waves = (ih, dvh).
// Producer/consumer split; P relay as [32 i][36 j] tile; packed b64 P-stores.
__global__ __launch_bounds__(256, 3) void attn_kernel(
    const _Float16* __restrict__ qh, const _Float16* __restrict__ kh,
    const _Float16* __restrict__ vTt, const float* __restrict__ bias2T,
    _Float16* __restrict__ attnp) {
  int bid = blockIdx.x;
  int it = 63 - (bid >> 5);
  int rem = bid & 31;
  int s = rem >> 1, b = rem & 1;
  int a = it >> 2, r = it & 3;
  int nblk = a + 1;
  if (s >= nblk) return;
  int T = 2*it + 2;
  int tlo = (s*T)/nblk, thi = ((s+1)*T)/nblk;
  int nt = thi - tlo;
  int base = it + 2*a*(a-1) + r*a;
  int slot = base + s;
  int i0 = it * 64;
  int tid = threadIdx.x;
  int lane = tid & 63, w = tid >> 6;
  int ih = w & 1;
  int dvh = w >> 1;
  bool prod = (dvh == 0);
  int lm = lane & 31, lg = lane >> 5;

  __shared__ __align__(16) char Vb[2][18432];   // V [256 dv][36 f16] stride 72B (2-way free)
  __shared__ __align__(16) char Kb[2][4352];    // K [32 j][68 f16] stride 136B
  __shared__ __align__(16) char Pbuf[2][2304];  // P per ih: [32 i][36 f16] stride 72B
  __shared__ float biasW[320];

  int jmaxv = thi*32 - 1;
  int dlo = i0 - jmaxv;
  int cnt = 64 + jmaxv - tlo*32;                // <= 320
  for (int k = tid; k < cnt; k += 256) {
    int d = dlo + k;
    biasW[k] = d < 0 ? -1e38f : bias2T[d];      // causal fold: -1e38 -> pv = 0
  }

  h8_t qf8[4];
  if (prod) {
    const _Float16* qp = qh + ((size_t)b*N_ + i0 + ih*32 + lm)*DQK_ + 8*lg;
#pragma unroll
    for (int kk = 0; kk < 4; ++kk) qf8[kk] = *(const h8_t*)(qp + 16*kk);
  }

  f16f accO[4];
#pragma unroll
  for (int i = 0; i < 4; ++i) accO[i] = zero16();

  const _Float16* kbase = kh + (size_t)b*N_*DQK_;
  const _Float16* vbase = vTt + (size_t)b*128*8192;   // 8192 f16 per 32-j tile
  int st = tid & 127;                           // stager index (threads 128..255)
  int kr = st >> 2, ks16 = st & 3;

  h8_t k8a, k8b, vr[8];
#define ISSUE_(JT) { \
  const _Float16* kp_ = kbase + (size_t)((JT)*32 + kr)*DQK_ + ks16*16; \
  k8a = *(const h8_t*)kp_; k8b = *(const h8_t*)(kp_ + 8); \
  const _Float16* vp_ = vbase + (size_t)(JT)*8192 + st*32; \
  _Pragma("unroll") for (int i = 0; i < 4; ++i) vr[i] = *(const h8_t*)(vp_ + i*8); \
  _Pragma("unroll") for (int i = 0; i < 4; ++i) vr[4+i] = *(const h8_t*)(vp_ + 4096 + i*8); }

#define COMMIT_(BI) { \
  char* kb_ = Kb[BI] + kr*136 + ks16*32; \
  *(h4_t*)kb_        = __builtin_shufflevector(k8a, k8a, 0,1,2,3); \
  *(h4_t*)(kb_ + 8)  = __builtin_shufflevector(k8a, k8a, 4,5,6,7); \
  *(h4_t*)(kb_ + 16) = __builtin_shufflevector(k8b, k8b, 0,1,2,3); \
  *(h4_t*)(kb_ + 24) = __builtin_shufflevector(k8b, k8b, 4,5,6,7); \
  char* va_ = Vb[BI] + st*72; \
  _Pragma("unroll") for (int i = 0; i < 4; ++i) { \
    *(h4_t*)(va_ + i*16)     = __builtin_shufflevector(vr[i], vr[i], 0,1,2,3); \
    *(h4_t*)(va_ + i*16 + 8) = __builtin_shufflevector(vr[i], vr[i], 4,5,6,7); } \
  char* vb2_ = Vb[BI] + (st + 128)*72; \
  _Pragma("unroll") for (int i = 0; i < 4; ++i) { \
    *(h4_t*)(vb2_ + i*16)     = __builtin_shufflevector(vr[4+i], vr[4+i], 0,1,2,3); \
    *(h4_t*)(vb2_ + i*16 + 8) = __builtin_shufflevector(vr[4+i], vr[4+i], 4,5,6,7); } }

  // prologue (stagers only): tile 0 committed; tile 1 in flight
  if (!prod) {
    ISSUE_(tlo);
    COMMIT_(0);
    if (nt > 1) ISSUE_(tlo + 1);
  }
  __syncthreads();

  const float C1 = 1.1283792f / 4096.f;
  int ibase = i0 + ih*32 + lm;
#pragma unroll 1
  for (int t = 0; t < nt; ++t) {
    if (prod) {
      // QK: S^T = sum_k mfma(K_frag, Q_frag), rows j cols i  (32x32x16, 4 MFMAs)
      const char* kb = Kb[t & 1];
      __builtin_amdgcn_s_setprio(1);
      f16f accS = zero16();
#pragma unroll
      for (int kk = 0; kk < 4; ++kk) {
        const char* ka = kb + lm*136 + 32*kk + 16*lg;
        h8_t kf8 = cat8_(*(const h4_t*)ka, *(const h4_t*)(ka + 8));
        accS = __builtin_amdgcn_mfma_f32_32x32x16_f16(kf8, qf8[kk], accS, 0, 0, 0);
      }
      __builtin_amdgcn_s_setprio(0);
      // softmax (once); pack per-k2 h4 groups (jl = 8*k2 + 4*lg + e) -> 4 b64 stores
      int idx0 = ibase - dlo - (tlo + t)*32 - 4*lg;
      h4_t pa[4];
#pragma unroll
      for (int rr = 0; rr < 16; ++rr) {
        float tt = fmaf(accS[rr], C1, biasW[idx0 - 8*(rr>>2) - (rr&3)]);
        float e = tt*fmaf(tt*tt, -0.101797f, -2.304877f);
        float u = exp2f(e);
        float pv = __builtin_amdgcn_rcpf(1.f + u);
        pa[rr>>2][rr&3] = (_Float16)pv;
      }
      char* pp = Pbuf[ih] + lm*72 + 8*lg;
#pragma unroll
      for (int k2 = 0; k2 < 4; ++k2) *(h4_t*)(pp + 16*k2) = pa[k2];
    } else {
      // stagers: distance-2 pipeline (commit tile t+1 issued one tile ago; issue t+2)
      if (t+1 < nt) COMMIT_((t+1) & 1);
      if (t+2 < nt) ISSUE_(tlo + t + 2);
    }
    __syncthreads();                            // B1: P + V/K(t+1) published
    // all waves: read P as PV A-fragments (row i=lm, k j = 16*ks2 + 8*lg + e)
    h8_t pa8[2];
    {
      const char* pp = Pbuf[ih] + lm*72;
#pragma unroll
      for (int ks2 = 0; ks2 < 2; ++ks2) {
        const char* pa_ = pp + 32*ks2 + 16*lg;
        pa8[ks2] = cat8_(*(const h4_t*)pa_, *(const h4_t*)(pa_ + 8));
      }
    }
    // PV: O += P @ V (this wave's dv half), 32x32x16, 8 MFMAs
    const char* vb = Vb[t & 1];
    __builtin_amdgcn_s_setprio(1);
#pragma unroll
    for (int ks2 = 0; ks2 < 2; ++ks2) {
#pragma unroll
      for (int dvb = 0; dvb < 4; ++dvb) {
        const char* va = vb + (dvh*128 + dvb*32 + lm)*72 + 32*ks2 + 16*lg;
        h8_t vf8 = cat8_(*(const h4_t*)va, *(const h4_t*)(va + 8));
        accO[dvb] = __builtin_amdgcn_mfma_f32_32x32x16_f16(pa8[ks2], vf8, accO[dvb], 0, 0, 0);
      }
    }
    __builtin_amdgcn_s_setprio(0);
    __syncthreads();                            // B2: reads of Vb[t&1]/Pbuf done
  }
#undef ISSUE_
#undef COMMIT_

  _Float16* op = attnp + ((size_t)b*544 + slot)*(64*256);
#pragma unroll
  for (int dvb = 0; dvb < 4; ++dvb) {
    int col = dvh*128 + dvb*32 + lm;
#pragma unroll
    for (int rr = 0; rr < 16; ++rr) {
      int row = ih*32 + 8*(rr>>2) + 4*lg + (rr&3);
      op[(size_t)row*256 + col] = (_Float16)accO[dvb][rr];
    }
  }
}

// gatedh = (sum of valid f16 attn partials) * reset(f16), cast to f16
__global__ void combine_gated(const _Float16* __restrict__ attnp,
                              const _Float16* __restrict__ resetbh,
                              _Float16* __restrict__ gatedh) {
  size_t fi = (size_t)blockIdx.x*256 + threadIdx.x;   // f4 index over 8192*256
  int c4 = (int)(fi & 63);
  int rr = (int)(fi >> 6);
  int b = rr >> 12, n = rr & 4095;
  int it = n >> 6, rowLocal = n & 63;
  int a = it >> 2, r = it & 3;
  int nblk = a + 1;
  int base = it + 2*a*(a-1) + r*a;
  const _Float16* ap = attnp + ((size_t)b*544 + base)*16384 + rowLocal*256 + c4*4;
  f4_t acc = (f4_t){0.f,0.f,0.f,0.f};
  for (int s2 = 0; s2 < nblk; ++s2) {
    h4_t pv = *(const h4_t*)(ap + (size_t)s2*16384);
#pragma unroll
    for (int j = 0; j < 4; ++j) acc[j] += (float)pv[j];
  }
  h4_t rg = *(const h4_t*)(resetbh + fi*4);
  h4_t hg;
#pragma unroll
  for (int j = 0; j < 4; ++j) hg[j] = (_Float16)(acc[j] * (float)rg[j]);
  *(h4_t*)(gatedh + fi*4) = hg;
}

// ---------------- final: H = silu(hemab + gated@Uh); out = u*H + (1-u)*x ----------------
__global__ __launch_bounds__(256) void final_mfma(
    const _Float16* __restrict__ gatedh, const _Float16* __restrict__ Uht,
    const _Float16* __restrict__ hemabh, const _Float16* __restrict__ updatebh,
    const float* __restrict__ x, float* __restrict__ out) {
  int rt = blockIdx.x >> 1, cs = blockIdx.x & 1;
  int tid = threadIdx.x;
  int lane = tid & 63, w = tid >> 6;
  int lr = lane & 15, lg = lane >> 4;
  int row0 = rt*64, c0 = cs*64;
  __shared__ _Float16 As[64][136];
  __shared__ _Float16 Ws[64][136];
  f4_t acc[4];
#pragma unroll
  for (int ns = 0; ns < 4; ++ns) acc[ns] = (f4_t){0.f,0.f,0.f,0.f};
#pragma unroll
  for (int kc = 0; kc < 2; ++kc) {
    __syncthreads();
#pragma unroll
    for (int i = 0; i < 4; ++i) {
      int idx = tid + i*256;
      int row = idx >> 4, seg = idx & 15;
      *(h8_t*)&As[row][seg*8] =
          *(const h8_t*)(gatedh + (size_t)(row0 + row)*DV_ + kc*128 + seg*8);
      *(h8_t*)&Ws[row][seg*8] =
          *(const h8_t*)(Uht + (size_t)(c0 + row)*DV_ + kc*128 + seg*8);
    }
    __syncthreads();
    h8_t af8[4];
#pragma unroll
    for (int kk = 0; kk < 4; ++kk) af8[kk] = *(const h8_t*)&As[w*16 + lr][32*kk + 8*lg];
#pragma unroll
    for (int ns = 0; ns < 4; ++ns) {
#pragma unroll
      for (int kk = 0; kk < 4; ++kk) {
        h8_t bf8 = *(const h8_t*)&Ws[ns*16 + lr][32*kk + 8*lg];
        acc[ns] = __builtin_amdgcn_mfma_f32_16x16x32_f16(af8[kk], bf8, acc[ns], 0, 0, 0);
      }
    }
  }
  int orow = row0 + w*16 + lg*4;
#pragma unroll
  for (int ns = 0; ns < 4; ++ns) {
    int col = c0 + ns*16 + lr;
#pragma unroll
    for (int r = 0; r < 4; ++r) {
      size_t o = (size_t)(orow + r)*D_ + col;
      float z = acc[ns][r] + (float)hemabh[o];
      float Hv = siluf_(z);
      float u  = (float)updatebh[o];
      out[o] = u*Hv + (1.f - u)*x[o];
    }
  }
}

extern "C" void kernel_launch(void* const* d_in, const int* in_sizes, int n_in,
                              void* d_out, int out_size, void* d_ws, size_t ws_size,
                              hipStream_t stream) {
  (void)in_sizes; (void)n_in; (void)out_size; (void)ws_size;
  const float* x         = (const float*)d_in[0];
  const float* expansion = (const float*)d_in[1];
  const float* reduction = (const float*)d_in[2];
  const float* alphas    = (const float*)d_in[3];
  const float* dampen    = (const float*)d_in[4];
  const float* Wqk       = (const float*)d_in[5];
  const float* bqk       = (const float*)d_in[6];
  const float* gamma     = (const float*)d_in[7];
  const float* beta      = (const float*)d_in[8];
  const float* Wv        = (const float*)d_in[9];
  const float* bv        = (const float*)d_in[10];
  const float* rel_table = (const float*)d_in[11];
  const float* Wr        = (const float*)d_in[12];
  const float* br        = (const float*)d_in[13];
  const float* Wu        = (const float*)d_in[14];
  const float* bu        = (const float*)d_in[15];
  const float* Wh        = (const float*)d_in[16];
  const float* Uh        = (const float*)d_in[17];
  const float* bh        = (const float*)d_in[18];
  float* out = (float*)d_out;

  char* p = (char*)d_ws;
  size_t off = 0;
  auto alloc = [&](size_t bytes) -> char* {
    char* r = p + off;
    off += (bytes + 255) & ~(size_t)255;
    return r;
  };
  float*    F       = (float*)alloc((size_t)B_*H_*D_*64*4);
  float*    carry   = (float*)alloc((size_t)B_*H_*D_*64*4);
  _Float16* emah    = (_Float16*)alloc((size_t)B_*N_*D_*2);
  _Float16* xh      = (_Float16*)alloc((size_t)B_*N_*D_*2);
  float*    bias2T  = (float*)alloc((size_t)N_*4);
  _Float16* Wt      = (_Float16*)alloc((size_t)832*128*2);
  float*    bcat    = (float*)alloc((size_t)832*4);
  _Float16* Uht     = (_Float16*)alloc((size_t)D_*DV_*2);
  _Float16* qh      = (_Float16*)alloc((size_t)B_*N_*DQK_*2);
  _Float16* kh      = (_Float16*)alloc((size_t)B_*N_*DQK_*2);
  _Float16* vTt     = (_Float16*)alloc((size_t)B_*DV_*N_*2);
  _Float16* resetbh = (_Float16*)alloc((size_t)B_*N_*DV_*2);
  _Float16* updatebh= (_Float16*)alloc((size_t)B_*N_*D_*2);
  _Float16* hemabh  = (_Float16*)alloc((size_t)B_*N_*D_*2);
  _Float16* gatedh  = (_Float16*)alloc((size_t)B_*N_*DV_*2);
  _Float16* attnp   = (_Float16*)alloc((size_t)B_*544*64*256*2);

  prep_all<<<560, 256, 0, stream>>>(Wqk, Wv, Wr, Wu, Wh, bqk, bv, br, bu, bh,
                                    Uh, rel_table, Wt, bcat, Uht, bias2T);
  ema_phase1<<<1024, 256, 0, stream>>>(x, expansion, alphas, dampen, F, xh);
  ema_carry<<<1024, 256, 0, stream>>>(F, alphas, dampen, carry);
  ema_phase2<<<1024, 256, 0, stream>>>(x, expansion, reduction, alphas, dampen, carry, emah);
  linear_mfma<<<128*13, 256, 0, stream>>>(emah, xh, Wt, bcat, gamma, beta,
                                          qh, kh, vTt, resetbh, updatebh, hemabh);
  attn_kernel<<<2048, 256, 0, stream>>>(qh, kh, vTt, bias2T, attnp);
  combine_gated<<<2048, 256, 0, stream>>>(attnp, resetbh, gatedh);
  final_mfma<<<256, 256, 0, stream>>>(gatedh, Uht, hemabh, updatebh, x, out);
}